// Round 2
// 341.558 us; speedup vs baseline: 1.0779x; 1.0779x over previous
//
#include <hip/hip_runtime.h>
#include <hip/hip_bf16.h>

// MQA cross-attention, MI355X bf16-MFMA pipeline.
// Round 6: 256² 8-phase GEMM with CORRECTED staging ledger (round-5 raced:
// t+2 halves staged into the live slot; and hipFuncSetAttribute under graph
// capture). Now: static 128KiB LDS (no runtime calls), B-halves of t+1 staged
// at ph0/ph1 (other slot), A-halves of t+2 staged at ph3 (issued after ph2's
// end-barrier, A-reads of live slot provably complete), vmcnt(4) once per
// K-tile (never 0 in steady state), setprio around MFMA cluster, T2 swizzle.
// Attention / LN / cast identical to the last passing 368µs version.
// B=4 S=4096 T=512 D=1024 Dtext=768 H=16 KVH=2 HD=64 REP=8

#define B_    4
#define S_    4096
#define T_    512
#define DM_   1024
#define DT_   768
#define H_    16
#define KVH_  2
#define HD_   64

#define GLOBAL_AS __attribute__((address_space(1)))
#define LDS_AS    __attribute__((address_space(3)))

typedef __bf16 bf16x8 __attribute__((ext_vector_type(8)));
typedef float  f32x4  __attribute__((ext_vector_type(4)));

// ---------------------------------------------------------------- cast x -> bf16
__global__ __launch_bounds__(256) void cast_f32_bf16(const float* __restrict__ in,
                                                     __hip_bfloat16* __restrict__ out) {
    int i = blockIdx.x * 256 + threadIdx.x;          // one float4 per thread
    float4 v = ((const float4*)in)[i];
    union { ushort4 u; __hip_bfloat16 h[4]; } p;
    p.h[0] = __float2bfloat16(v.x);
    p.h[1] = __float2bfloat16(v.y);
    p.h[2] = __float2bfloat16(v.z);
    p.h[3] = __float2bfloat16(v.w);
    ((ushort4*)out)[i] = p.u;
}

// ---------------------------------------------- transpose+cast W[K][N] -> Wt[N][K] bf16
__global__ __launch_bounds__(256) void transpose_cast(const float* __restrict__ in,
                                                      __hip_bfloat16* __restrict__ out,
                                                      int R, int C) {
    __shared__ float tile[32][33];
    int tx = threadIdx.x, ty = threadIdx.y;           // block (32,8)
    int r0 = blockIdx.y * 32, c0 = blockIdx.x * 32;
#pragma unroll
    for (int k = 0; k < 4; k++)
        tile[ty + 8 * k][tx] = in[(size_t)(r0 + ty + 8 * k) * C + c0 + tx];
    __syncthreads();
#pragma unroll
    for (int k = 0; k < 4; k++)
        out[(size_t)(c0 + ty + 8 * k) * R + r0 + tx] = __float2bfloat16(tile[tx][ty + 8 * k]);
}

// --------------------------------- LayerNorm(text) @ Wkv -> K [b,g,t,d], Vt [b,g,d,t] (bf16)
__global__ __launch_bounds__(256) void ln_kv_kernel(const float* __restrict__ text,
                                                    const float* __restrict__ lnw,
                                                    const float* __restrict__ lnb,
                                                    const float* __restrict__ Wkv,
                                                    __hip_bfloat16* __restrict__ Kg,
                                                    __hip_bfloat16* __restrict__ Vt) {
    __shared__ float tn[8][DT_];
    __shared__ float red[2][256];
    int tid = threadIdx.x;
    int b  = blockIdx.x >> 6;                 // 64 blocks per batch
    int t0 = (blockIdx.x & 63) * 8;           // 8 text rows per block

    for (int j = 0; j < 8; j++) {
        const float* row = text + (size_t)(b * T_ + t0 + j) * DT_;
        float v0 = row[tid], v1 = row[tid + 256], v2 = row[tid + 512];
        red[0][tid] = v0 + v1 + v2;
        red[1][tid] = v0 * v0 + v1 * v1 + v2 * v2;
        __syncthreads();
        for (int ofs = 128; ofs > 0; ofs >>= 1) {
            if (tid < ofs) { red[0][tid] += red[0][tid + ofs]; red[1][tid] += red[1][tid + ofs]; }
            __syncthreads();
        }
        float mu  = red[0][0] * (1.0f / DT_);
        float var = red[1][0] * (1.0f / DT_) - mu * mu;
        float rs  = rsqrtf(var + 1e-5f);
        tn[j][tid]       = (v0 - mu) * rs * lnw[tid]       + lnb[tid];
        tn[j][tid + 256] = (v1 - mu) * rs * lnw[tid + 256] + lnb[tid + 256];
        tn[j][tid + 512] = (v2 - mu) * rs * lnw[tid + 512] + lnb[tid + 512];
        __syncthreads();   // protect red[] before next row
    }

    float acc[8] = {0, 0, 0, 0, 0, 0, 0, 0};
    for (int k = 0; k < DT_; k++) {
        float w = Wkv[(size_t)k * 256 + tid];  // coalesced; broadcast tn reads
#pragma unroll
        for (int j = 0; j < 8; j++) acc[j] += tn[j][k] * w;
    }
    int c = tid;
    int isV = c >> 7;
    int cc = c & 127, g = cc >> 6, d = cc & 63;
#pragma unroll
    for (int j = 0; j < 8; j++) {
        int t = t0 + j;
        __hip_bfloat16 hv = __float2bfloat16(acc[j]);
        if (!isV) Kg[((size_t)(b * KVH_ + g) * T_ + t) * HD_ + d] = hv;
        else      Vt[((size_t)(b * KVH_ + g) * HD_ + d) * T_ + t] = hv;
    }
}

// ------------------------------------------- C[M,N] = A[M,K] * Bt[N,K]^T  (bf16 MFMA)
// 256x256 tile, BK=64, 512 threads / 8 waves (2M x 4N), per-wave 128x64 output.
// Static LDS 128KiB: 2 dbuf slots x (A 256x64 + B 256x64) bf16, rows of 8x16B
// units with unit u stored at u^(row&7) (conflict-free ds_read_b128).
// Per K-tile: 4 phases = C-quadrants (mh,nh). Each phase:
//   [ds_read frags (A only at nh==0, reused); stage; s_barrier;
//    sched_barrier; setprio(1); 16 MFMA; setprio(0); (ph3: counted vmcnt);
//    s_barrier; sched_barrier]
// Stage ledger (race-free with 2 slots):
//   ph0: B0(t+1), ph1: B1(t+1)    -> other slot, always safe
//   ph3: A0(t+2), A1(t+2)         -> live slot, but issued AFTER ph2's end
//        barrier; all A-reads of the live slot complete by then (A is read
//        only at nh==0 phases, last at ph2, drained before its end barrier).
//   B of t+2 is staged during tile t+1 (ph0/ph1) - live slot never written
//   while B still readable.  End-of-tile wait: vmcnt(4) leaves exactly
//   {A0,A1 of t+2} (2 loads/thread each... 2 half-tiles = 4 loads) in flight
//   and guarantees tile t+1 fully landed.  Tail: t==NT-2 -> vmcnt(0).
// EPI 0: bf16 out, *scale.  EPI 1: f32 out, + bias.
template <int EPI>
__global__ __launch_bounds__(512, 2) void gemm256(const __hip_bfloat16* __restrict__ A,
                                                  const __hip_bfloat16* __restrict__ Bt,
                                                  void* __restrict__ Cout,
                                                  const float* __restrict__ bias,
                                                  float scale, int M, int N, int K) {
    __shared__ __bf16 lds[65536];             // 128 KiB static
    const int tid = threadIdx.x;
    const int w = tid >> 6, lane = tid & 63, q = lane >> 4, cL = lane & 15;
    const int wm = w >> 2, wn = w & 3;        // 2 x 4 wave grid
    const size_t m0 = (size_t)blockIdx.y * 256, n0 = (size_t)blockIdx.x * 256;
    const __bf16* Ab = (const __bf16*)A + m0 * K;
    const __bf16* Bb = (const __bf16*)Bt + n0 * K;
    const int NT = K >> 6;                    // K-tiles of 64

    // staging source/dest offsets (per thread, constant over tiles).
    // half-tile = 128 rows x 64 cols = 1024 16B-units; thread stages units
    // id = tid, tid+512. dest unit: row r=id>>3, pos p=id&7 holds source
    // unit u = p ^ (r&7).
    int srcoff[2], dstoff[2];
#pragma unroll
    for (int it = 0; it < 2; ++it) {
        int id = tid + it * 512;
        int r = id >> 3, u = (id & 7) ^ (r & 7);
        srcoff[it] = r * K + u * 8;
        dstoff[it] = id * 8;
    }

    // fragment read constants: frag row R has R&7 == cL&7 (other terms are
    // multiples of 8/16), so the swizzle term is thread-constant.
    const int swz0 = ((0 + q) ^ (cL & 7)) * 8;   // kk=0 (cols 0..31) unit
    const int swz1 = ((4 + q) ^ (cL & 7)) * 8;   // kk=1 (cols 32..63) unit
    const int baseA = (wm * 128 + cL) * 64;
    const int baseB = (wn * 64 + cL) * 64;

    f32x4 acc[8][4] = {};

    auto STAGE = [&](int isB, int j, int tt) {   // half-tile (A/B, rows j*128..) of K-tile tt
        const __bf16* g = (isB ? Bb : Ab) + (size_t)j * 128 * K + (size_t)tt * 64;
        const int sb = (tt & 1) * 32768 + isB * 16384 + j * 8192;
#pragma unroll
        for (int it = 0; it < 2; ++it)
            __builtin_amdgcn_global_load_lds(
                (const GLOBAL_AS void*)(g + srcoff[it]),
                (LDS_AS void*)(&lds[sb + dstoff[it]]), 16, 0, 0);
    };

    // prologue: tile0 complete + A-halves of tile1 (as-if issued at "t=-1 ph3")
    STAGE(0, 0, 0); STAGE(0, 1, 0); STAGE(1, 0, 0); STAGE(1, 1, 0);
    if (NT > 1) { STAGE(0, 0, 1); STAGE(0, 1, 1); }
    asm volatile("s_waitcnt vmcnt(4)" ::: "memory");   // tile0 landed; A(1) may fly
    __builtin_amdgcn_s_barrier();
    __builtin_amdgcn_sched_barrier(0);

    for (int t = 0; t < NT; ++t) {
        const int sb = (t & 1) * 32768;
        const __bf16* As = lds + sb;
        const __bf16* Bs = lds + sb + 16384;
        bf16x8 af[4][2];                       // A-half frags, reused across nh pair
#pragma unroll
        for (int ph = 0; ph < 4; ++ph) {
            const int mh = ph >> 1, nh = ph & 1;
            if (nh == 0) {                     // A-half mh: 8 x ds_read_b128
#pragma unroll
                for (int m = 0; m < 4; ++m) {
                    int ro = baseA + mh * 4096 + m * 1024;
                    af[m][0] = *(const bf16x8*)&As[ro + swz0];
                    af[m][1] = *(const bf16x8*)&As[ro + swz1];
                }
            }
            bf16x8 bq[2][2];                   // B-half nh: 4 x ds_read_b128
#pragma unroll
            for (int n = 0; n < 2; ++n) {
                int ro = baseB + nh * 2048 + n * 1024;
                bq[n][0] = *(const bf16x8*)&Bs[ro + swz0];
                bq[n][1] = *(const bf16x8*)&Bs[ro + swz1];
            }
            // stage (issue-only; see ledger in header comment)
            if (ph == 0)      { if (t + 1 < NT) STAGE(1, 0, t + 1); }
            else if (ph == 1) { if (t + 1 < NT) STAGE(1, 1, t + 1); }
            else if (ph == 3 && t + 2 < NT) { STAGE(0, 0, t + 2); STAGE(0, 1, t + 2); }

            __builtin_amdgcn_s_barrier();
            __builtin_amdgcn_sched_barrier(0);
            __builtin_amdgcn_s_setprio(1);
#pragma unroll
            for (int m = 0; m < 4; ++m)
#pragma unroll
                for (int n = 0; n < 2; ++n) {
                    f32x4* a = &acc[mh * 4 + m][nh * 2 + n];
                    *a = __builtin_amdgcn_mfma_f32_16x16x32_bf16(af[m][0], bq[n][0], *a, 0, 0, 0);
                    *a = __builtin_amdgcn_mfma_f32_16x16x32_bf16(af[m][1], bq[n][1], *a, 0, 0, 0);
                }
            __builtin_amdgcn_s_setprio(0);
            if (ph == 3) {                     // counted wait, once per K-tile
                if (t + 2 < NT)      asm volatile("s_waitcnt vmcnt(4)" ::: "memory");
                else if (t + 1 < NT) asm volatile("s_waitcnt vmcnt(0)" ::: "memory");
            }
            __builtin_amdgcn_s_barrier();
            __builtin_amdgcn_sched_barrier(0);
        }
    }

    // epilogue: C/D row = 4*quad + reg, col = lane&15
#pragma unroll
    for (int jn = 0; jn < 4; ++jn) {
        size_t col = n0 + wn * 64 + jn * 16 + cL;
        float bb = 0.0f;
        if (EPI == 1) bb = bias[col];
#pragma unroll
        for (int im = 0; im < 8; ++im) {
            size_t r = m0 + wm * 128 + im * 16 + 4 * q;
#pragma unroll
            for (int ii = 0; ii < 4; ++ii) {
                float v = acc[im][jn][ii];
                if (EPI == 0)
                    ((__hip_bfloat16*)Cout)[(r + ii) * N + col] = __float2bfloat16(v * scale);
                else
                    ((float*)Cout)[(r + ii) * N + col] = v + bb;
            }
        }
    }
}

// ---------------------------------------------- flash attention, LDS-staged K/V
// block = 256 threads / 4 waves, 128 S-rows (32/wave) for one (b,h).
// T in 8 chunks of 64: K-chunk [t][d] 8KB + V-chunk [d][t] 8KB staged via
// global_load_lds, 16B units XOR-swizzled by row (2-way-free frag reads).
// No-max softmax (scores ~N(0,0.36)); P via per-wave LDS round-trip.
__global__ __launch_bounds__(256, 4) void attn_kernel(const __hip_bfloat16* __restrict__ Qs,
                                                      const __hip_bfloat16* __restrict__ Kg,
                                                      const __hip_bfloat16* __restrict__ Vt,
                                                      __hip_bfloat16* __restrict__ Oc) {
    __shared__ __bf16 Ks[64 * 64];   // [t=64][d=64], swizzled units
    __shared__ __bf16 Vs[64 * 64];   // [d=64][t=64], swizzled units
    __shared__ __bf16 Ps[4][1024];   // per-wave 2KB: two 16x32 A-frag blocks (mi=0,1)
    int tid = threadIdx.x;
    int w = tid >> 6, lane = tid & 63, q = lane >> 4, cL = lane & 15;
    int bh = blockIdx.y;
    int b = bh >> 4, h = bh & 15, g = h >> 3;
    int s0 = blockIdx.x * 128 + w * 32;

    const __bf16* Qb = (const __bf16*)Qs;
    const __bf16* Kb = (const __bf16*)Kg + (size_t)(b * KVH_ + g) * T_ * HD_;
    const __bf16* Vb = (const __bf16*)Vt + (size_t)(b * KVH_ + g) * HD_ * T_;
    __bf16* pw = &Ps[w][0];

    // staging source offsets (elements), constant over chunks; add t0*64 (K) / t0 (V)
    int ksoff[2], vsoff[2];
#pragma unroll
    for (int it = 0; it < 2; it++) {
        int U = tid + it * 256;                 // dest 16B unit
        int r = U >> 3, us = (U & 7) ^ (r & 7); // row, swizzled source unit
        ksoff[it] = r * HD_ + us * 8;           // K: row=t_loc (64 elem rows)
        vsoff[it] = r * T_  + us * 8;           // V: row=d     (512 elem rows)
    }

    // Q A-fragments: 2 m-frags of 16 rows; k = d (2 halves of 32). Q pre-scaled 1/8.
    bf16x8 aq[2][2];
#pragma unroll
    for (int mi = 0; mi < 2; mi++) {
        size_t base = ((size_t)(b * S_) + s0 + mi * 16 + cL) * DM_ + h * HD_ + 8 * q;
        aq[mi][0] = *(const bf16x8*)(Qb + base);
        aq[mi][1] = *(const bf16x8*)(Qb + base + 32);
    }

    float lpart[2][4] = {};
    f32x4 oacc[2][4] = {};

#pragma unroll 1
    for (int tc = 0; tc < 8; tc++) {          // T-chunk of 64
        int t0 = tc * 64;
#pragma unroll
        for (int it = 0; it < 2; it++) {
            int U = tid + it * 256;
            __builtin_amdgcn_global_load_lds(
                (const GLOBAL_AS void*)(Kb + (size_t)t0 * HD_ + ksoff[it]),
                (LDS_AS void*)(&Ks[U * 8]), 16, 0, 0);
            __builtin_amdgcn_global_load_lds(
                (const GLOBAL_AS void*)(Vb + t0 + vsoff[it]),
                (LDS_AS void*)(&Vs[U * 8]), 16, 0, 0);
        }
        __syncthreads();

        // scores S[32 x 64] = Q * K^T ; K-frag units swizzled: unit u at u^(R&7)
        f32x4 sc[2][4];
#pragma unroll
        for (int nt = 0; nt < 4; nt++) {
            int R = 16 * nt + cL;
            bf16x8 k0 = *(const bf16x8*)&Ks[R * 64 + ((q ^ (R & 7)) * 8)];
            bf16x8 k1 = *(const bf16x8*)&Ks[R * 64 + (((4 + q) ^ (R & 7)) * 8)];
#pragma unroll
            for (int mi = 0; mi < 2; mi++) {
                f32x4 a = {0.f, 0.f, 0.f, 0.f};
                a = __builtin_amdgcn_mfma_f32_16x16x32_bf16(aq[mi][0], k0, a, 0, 0, 0);
                a = __builtin_amdgcn_mfma_f32_16x16x32_bf16(aq[mi][1], k1, a, 0, 0, 0);
                sc[mi][nt] = a;
            }
        }

        // exp (no max-sub), per-lane partial row sums
#pragma unroll
        for (int mi = 0; mi < 2; mi++)
#pragma unroll
            for (int i = 0; i < 4; i++) {
                float ls = 0.f;
#pragma unroll
                for (int nt = 0; nt < 4; nt++) {
                    float e = __expf(sc[mi][nt][i]); sc[mi][nt][i] = e; ls += e;
                }
                lpart[mi][i] += ls;
            }

        // P round-trip + PV per 32-t sub-chunk (same-wave LDS, no barrier)
#pragma unroll
        for (int ksc = 0; ksc < 2; ksc++) {
#pragma unroll
            for (int mi = 0; mi < 2; mi++)
#pragma unroll
                for (int half = 0; half < 2; half++) {
                    int nt = 2 * ksc + half;
                    int tin = half * 16 + cL;
                    int off = mi * 512 + (((tin >> 3) * 16 + 4 * q) * 8) + (tin & 7);
#pragma unroll
                    for (int i = 0; i < 4; i++)
                        pw[off + i * 8] = (__bf16)sc[mi][nt][i];
                }
            bf16x8 pa0 = *(const bf16x8*)&pw[lane * 8];
            bf16x8 pa1 = *(const bf16x8*)&pw[512 + lane * 8];
#pragma unroll
            for (int nd = 0; nd < 4; nd++) {
                int D = 16 * nd + cL;
                bf16x8 bv = *(const bf16x8*)&Vs[D * 64 + (((4 * ksc + q) ^ (D & 7)) * 8)];
                oacc[0][nd] = __builtin_amdgcn_mfma_f32_16x16x32_bf16(pa0, bv, oacc[0][nd], 0, 0, 0);
                oacc[1][nd] = __builtin_amdgcn_mfma_f32_16x16x32_bf16(pa1, bv, oacc[1][nd], 0, 0, 0);
            }
        }
        __syncthreads();   // all waves done with Ks/Vs before restage
    }

    // row-sum reduce across the 16 lanes sharing quad q, then write O
#pragma unroll
    for (int mi = 0; mi < 2; mi++) {
        float rinv[4];
#pragma unroll
        for (int i = 0; i < 4; i++) {
            float l = lpart[mi][i];
            l += __shfl_xor(l, 1); l += __shfl_xor(l, 2);
            l += __shfl_xor(l, 4); l += __shfl_xor(l, 8);
            rinv[i] = 1.0f / l;
        }
#pragma unroll
        for (int nd = 0; nd < 4; nd++)
#pragma unroll
            for (int i = 0; i < 4; i++) {
                float v = oacc[mi][nd][i] * rinv[i];
                size_t s = (size_t)(b * S_) + s0 + mi * 16 + 4 * q + i;
                Oc[s * DM_ + h * HD_ + nd * 16 + cL] = __float2bfloat16(v);
            }
    }
}

// ---------------------------------------------------------------------- launch
extern "C" void kernel_launch(void* const* d_in, const int* in_sizes, int n_in,
                              void* d_out, int out_size, void* d_ws, size_t ws_size,
                              hipStream_t stream) {
    const float* x    = (const float*)d_in[0];
    const float* text = (const float*)d_in[1];
    const float* lnw  = (const float*)d_in[2];
    const float* lnb  = (const float*)d_in[3];
    const float* Wq   = (const float*)d_in[4];
    const float* Wkv  = (const float*)d_in[5];
    const float* Wout = (const float*)d_in[6];
    const float* bout = (const float*)d_in[7];

    char* ws = (char*)d_ws;
    __hip_bfloat16* xbf = (__hip_bfloat16*)(ws);              // 33.5 MB; reused as Oc
    __hip_bfloat16* Qs  = (__hip_bfloat16*)(ws + 33554432);   // 33.5 MB
    __hip_bfloat16* Wqt = (__hip_bfloat16*)(ws + 67108864);   // 2 MB
    __hip_bfloat16* Wot = (__hip_bfloat16*)(ws + 69206016);   // 2 MB
    __hip_bfloat16* Kg  = (__hip_bfloat16*)(ws + 71303168);   // 0.5 MB
    __hip_bfloat16* Vtp = (__hip_bfloat16*)(ws + 71827456);   // 0.5 MB

    cast_f32_bf16<<<dim3((B_ * S_ * DM_) / 4 / 256), dim3(256), 0, stream>>>(x, xbf);
    transpose_cast<<<dim3(32, 32), dim3(32, 8), 0, stream>>>(Wq, Wqt, DM_, DM_);
    transpose_cast<<<dim3(32, 32), dim3(32, 8), 0, stream>>>(Wout, Wot, DM_, DM_);
    ln_kv_kernel<<<dim3(B_ * T_ / 8), dim3(256), 0, stream>>>(text, lnw, lnb, Wkv, Kg, Vtp);

    // Q = (x @ Wq) * (1/sqrt(64))  [bf16]  -- grid (1024/256, 16384/256) = 256 blocks
    gemm256<0><<<dim3(DM_ / 256, (B_ * S_) / 256), dim3(512), 0, stream>>>(
        xbf, Wqt, (void*)Qs, nullptr, 0.125f, B_ * S_, DM_, DM_);

    // attention -> Oc (reuses xbf region; x is dead after Q-proj)
    attn_kernel<<<dim3(S_ / 128, B_ * H_), dim3(256), 0, stream>>>(Qs, Kg, Vtp, xbf);

    // out = Oc @ Wout + bout  [f32]
    gemm256<1><<<dim3(DM_ / 256, (B_ * S_) / 256), dim3(512), 0, stream>>>(
        xbf, Wot, d_out, bout, 1.0f, B_ * S_, DM_, DM_);
}

// Round 3
// 301.683 us; speedup vs baseline: 1.2204x; 1.1322x over previous
//
#include <hip/hip_runtime.h>
#include <hip/hip_bf16.h>

// MQA cross-attention, MI355X bf16-MFMA pipeline.
// Round 7: ln_kv_kernel (65.5µs, MfmaUtil=0, latency-bound VALU GEMM) split:
//   ln_norm  - LayerNorm only, wave-per-row, f32x4 loads, shuffle reduce,
//              bf16 out  (~3µs, memory-bound)
//   kv_gemm  - [2048x768]@[768x256]^T bf16 MFMA, 64x64 tile BK=32,
//              double-buffered LDS, round-0-proven XOR swizzle (~5-10µs)
//   + transpose_cast of Wkv -> Wkvt[256][768] bf16.
// tnb/Wkvt parked in the Qs region (dead until gemm256<0> writes Qs, which is
// strictly after kv_gemm on the stream). gemm256 (8-phase, passing) and
// attn_kernel unchanged.
// B=4 S=4096 T=512 D=1024 Dtext=768 H=16 KVH=2 HD=64 REP=8

#define B_    4
#define S_    4096
#define T_    512
#define DM_   1024
#define DT_   768
#define H_    16
#define KVH_  2
#define HD_   64

#define GLOBAL_AS __attribute__((address_space(1)))
#define LDS_AS    __attribute__((address_space(3)))

typedef __bf16 bf16x8 __attribute__((ext_vector_type(8)));
typedef float  f32x4  __attribute__((ext_vector_type(4)));

// ---------------------------------------------------------------- cast x -> bf16
__global__ __launch_bounds__(256) void cast_f32_bf16(const float* __restrict__ in,
                                                     __hip_bfloat16* __restrict__ out) {
    int i = blockIdx.x * 256 + threadIdx.x;          // one float4 per thread
    float4 v = ((const float4*)in)[i];
    union { ushort4 u; __hip_bfloat16 h[4]; } p;
    p.h[0] = __float2bfloat16(v.x);
    p.h[1] = __float2bfloat16(v.y);
    p.h[2] = __float2bfloat16(v.z);
    p.h[3] = __float2bfloat16(v.w);
    ((ushort4*)out)[i] = p.u;
}

// ---------------------------------------------- transpose+cast W[R][C] -> Wt[C][R] bf16
__global__ __launch_bounds__(256) void transpose_cast(const float* __restrict__ in,
                                                      __hip_bfloat16* __restrict__ out,
                                                      int R, int C) {
    __shared__ float tile[32][33];
    int tx = threadIdx.x, ty = threadIdx.y;           // block (32,8)
    int r0 = blockIdx.y * 32, c0 = blockIdx.x * 32;
#pragma unroll
    for (int k = 0; k < 4; k++)
        tile[ty + 8 * k][tx] = in[(size_t)(r0 + ty + 8 * k) * C + c0 + tx];
    __syncthreads();
#pragma unroll
    for (int k = 0; k < 4; k++)
        out[(size_t)(c0 + ty + 8 * k) * R + r0 + tx] = __float2bfloat16(tile[tx][ty + 8 * k]);
}

// --------------------------------- LayerNorm(text) -> tnb bf16 [B*T][768]
// one row per wave (2 rows sequentially), float4 loads, 64-lane shuffle reduce.
__global__ __launch_bounds__(256) void ln_norm(const float* __restrict__ text,
                                               const float* __restrict__ lnw,
                                               const float* __restrict__ lnb,
                                               __hip_bfloat16* __restrict__ tnb) {
    int tid = threadIdx.x;
    int w = tid >> 6, lane = tid & 63;
    int row0 = blockIdx.x * 8 + w * 2;               // 8 rows/block, 2 rows/wave
#pragma unroll
    for (int rr = 0; rr < 2; ++rr) {
        int row = row0 + rr;
        const float4* src = (const float4*)(text + (size_t)row * DT_);
        float4 v[3];
        float s = 0.f, s2 = 0.f;
#pragma unroll
        for (int j = 0; j < 3; ++j) {
            v[j] = src[lane + 64 * j];
            s  += v[j].x + v[j].y + v[j].z + v[j].w;
            s2 += v[j].x * v[j].x + v[j].y * v[j].y + v[j].z * v[j].z + v[j].w * v[j].w;
        }
#pragma unroll
        for (int ofs = 1; ofs < 64; ofs <<= 1) {
            s  += __shfl_xor(s, ofs);
            s2 += __shfl_xor(s2, ofs);
        }
        float mu  = s * (1.0f / DT_);
        float var = s2 * (1.0f / DT_) - mu * mu;
        float rs  = rsqrtf(var + 1e-5f);
#pragma unroll
        for (int j = 0; j < 3; ++j) {
            float4 wv = ((const float4*)lnw)[lane + 64 * j];
            float4 bv = ((const float4*)lnb)[lane + 64 * j];
            union { ushort4 u; __hip_bfloat16 h[4]; } p;
            p.h[0] = __float2bfloat16((v[j].x - mu) * rs * wv.x + bv.x);
            p.h[1] = __float2bfloat16((v[j].y - mu) * rs * wv.y + bv.y);
            p.h[2] = __float2bfloat16((v[j].z - mu) * rs * wv.z + bv.z);
            p.h[3] = __float2bfloat16((v[j].w - mu) * rs * wv.w + bv.w);
            ((ushort4*)(tnb + (size_t)row * DT_))[lane + 64 * j] = p.u;
        }
    }
}

// ----------------------- KV projection: C[2048,256] = tnb[2048,768] @ Wkvt[256,768]^T
// bf16 MFMA, 64x64 tile, BK=32, double-buffered LDS, XOR-swizzled 16B units
// (128B super-rows: unit U=(row&1)*4+u stored at U^(sr&7); proven 0-conflict).
// Epilogue scatters to K [b,g,t,d] / Vt [b,g,d,t].
__global__ __launch_bounds__(256) void kv_gemm(const __hip_bfloat16* __restrict__ Atn,
                                               const __hip_bfloat16* __restrict__ Wkvt,
                                               __hip_bfloat16* __restrict__ Kg,
                                               __hip_bfloat16* __restrict__ Vt) {
    __shared__ __bf16 As[2][64 * 32];
    __shared__ __bf16 Bs[2][64 * 32];
    const int tid = threadIdx.x;
    const int w = tid >> 6, lane = tid & 63, q = lane >> 4, cL = lane & 15;
    const size_t m0 = (size_t)blockIdx.y * 64, n0 = (size_t)blockIdx.x * 64;
    const int K = DT_;                 // 768
    const int NT = K / 32;             // 24

    // staging map: one 16B unit per thread per matrix (256 units = 64x32 bf16)
    int srcoff, dstoff;
    {
        int id = tid;
        int sr = id >> 3, U = (id & 7) ^ (sr & 7);
        int row = 2 * sr + (U >> 2), ko = (U & 3) * 8;
        srcoff = row * K + ko;
        dstoff = id * 8;
    }
    const __bf16* Ab = (const __bf16*)Atn + m0 * K;
    const __bf16* Bb = (const __bf16*)Wkvt + n0 * K;

    // fragment LDS element offsets
    auto frag_off = [&](int R) {
        return (R >> 1) * 64 + ((((R & 1) * 4 + q) ^ ((R >> 1) & 7)) * 8);
    };
    const int offA = frag_off(w * 16 + cL);
    int offB[4];
#pragma unroll
    for (int nf = 0; nf < 4; ++nf) offB[nf] = frag_off(nf * 16 + cL);

    f32x4 acc[4] = {};

    auto STAGE = [&](int buf, int t) {
        int k0 = t * 32;
        __builtin_amdgcn_global_load_lds((const GLOBAL_AS void*)(Ab + srcoff + k0),
                                         (LDS_AS void*)(&As[buf][dstoff]), 16, 0, 0);
        __builtin_amdgcn_global_load_lds((const GLOBAL_AS void*)(Bb + srcoff + k0),
                                         (LDS_AS void*)(&Bs[buf][dstoff]), 16, 0, 0);
    };

    STAGE(0, 0);
    __syncthreads();                       // drains vmcnt(0) before barrier
    for (int t = 0; t < NT; ++t) {
        int cur = t & 1;
        if (t + 1 < NT) STAGE(cur ^ 1, t + 1);   // issue next tile (other buffer)
        bf16x8 af = *(const bf16x8*)&As[cur][offA];
#pragma unroll
        for (int nf = 0; nf < 4; ++nf) {
            bf16x8 bf = *(const bf16x8*)&Bs[cur][offB[nf]];
            acc[nf] = __builtin_amdgcn_mfma_f32_16x16x32_bf16(af, bf, acc[nf], 0, 0, 0);
        }
        __syncthreads();                   // next-tile loads landed + reads done
    }

    // epilogue: C/D row = 4*quad + reg, col = lane&15 ; scatter to K/Vt layouts
#pragma unroll
    for (int nf = 0; nf < 4; ++nf) {
        int n = (int)n0 + nf * 16 + cL;
        int isV = n >> 7, g = (n >> 6) & 1, d = n & 63;
#pragma unroll
        for (int ii = 0; ii < 4; ++ii) {
            int m = (int)m0 + w * 16 + 4 * q + ii;
            int b = m >> 9, tt = m & 511;
            __hip_bfloat16 hv = __float2bfloat16(acc[nf][ii]);
            if (!isV) Kg[((size_t)(b * KVH_ + g) * T_ + tt) * HD_ + d] = hv;
            else      Vt[((size_t)(b * KVH_ + g) * HD_ + d) * T_ + tt] = hv;
        }
    }
}

// ------------------------------------------- C[M,N] = A[M,K] * Bt[N,K]^T  (bf16 MFMA)
// 256x256 tile, BK=64, 512 threads / 8 waves (2M x 4N), per-wave 128x64 output.
// Static LDS 128KiB: 2 dbuf slots x (A 256x64 + B 256x64) bf16, rows of 8x16B
// units with unit u stored at u^(row&7) (conflict-free ds_read_b128).
// Per K-tile: 4 phases = C-quadrants (mh,nh). Stage ledger (race-free):
//   ph0: B0(t+1), ph1: B1(t+1) -> other slot; ph3: A0,A1(t+2) -> live slot but
//   issued after ph2's end barrier (all A-reads of live slot complete).
//   End-of-tile vmcnt(4) leaves {A0,A1 of t+2} in flight, guarantees t+1 landed.
// EPI 0: bf16 out, *scale.  EPI 1: f32 out, + bias.
template <int EPI>
__global__ __launch_bounds__(512, 2) void gemm256(const __hip_bfloat16* __restrict__ A,
                                                  const __hip_bfloat16* __restrict__ Bt,
                                                  void* __restrict__ Cout,
                                                  const float* __restrict__ bias,
                                                  float scale, int M, int N, int K) {
    __shared__ __bf16 lds[65536];             // 128 KiB static
    const int tid = threadIdx.x;
    const int w = tid >> 6, lane = tid & 63, q = lane >> 4, cL = lane & 15;
    const int wm = w >> 2, wn = w & 3;        // 2 x 4 wave grid
    const size_t m0 = (size_t)blockIdx.y * 256, n0 = (size_t)blockIdx.x * 256;
    const __bf16* Ab = (const __bf16*)A + m0 * K;
    const __bf16* Bb = (const __bf16*)Bt + n0 * K;
    const int NT = K >> 6;                    // K-tiles of 64

    int srcoff[2], dstoff[2];
#pragma unroll
    for (int it = 0; it < 2; ++it) {
        int id = tid + it * 512;
        int r = id >> 3, u = (id & 7) ^ (r & 7);
        srcoff[it] = r * K + u * 8;
        dstoff[it] = id * 8;
    }

    const int swz0 = ((0 + q) ^ (cL & 7)) * 8;   // kk=0 (cols 0..31) unit
    const int swz1 = ((4 + q) ^ (cL & 7)) * 8;   // kk=1 (cols 32..63) unit
    const int baseA = (wm * 128 + cL) * 64;
    const int baseB = (wn * 64 + cL) * 64;

    f32x4 acc[8][4] = {};

    auto STAGE = [&](int isB, int j, int tt) {   // half-tile (A/B, rows j*128..) of K-tile tt
        const __bf16* g = (isB ? Bb : Ab) + (size_t)j * 128 * K + (size_t)tt * 64;
        const int sb = (tt & 1) * 32768 + isB * 16384 + j * 8192;
#pragma unroll
        for (int it = 0; it < 2; ++it)
            __builtin_amdgcn_global_load_lds(
                (const GLOBAL_AS void*)(g + srcoff[it]),
                (LDS_AS void*)(&lds[sb + dstoff[it]]), 16, 0, 0);
    };

    // prologue: tile0 complete + A-halves of tile1 (as-if issued at "t=-1 ph3")
    STAGE(0, 0, 0); STAGE(0, 1, 0); STAGE(1, 0, 0); STAGE(1, 1, 0);
    if (NT > 1) { STAGE(0, 0, 1); STAGE(0, 1, 1); }
    asm volatile("s_waitcnt vmcnt(4)" ::: "memory");   // tile0 landed; A(1) may fly
    __builtin_amdgcn_s_barrier();
    __builtin_amdgcn_sched_barrier(0);

    for (int t = 0; t < NT; ++t) {
        const int sb = (t & 1) * 32768;
        const __bf16* As = lds + sb;
        const __bf16* Bs = lds + sb + 16384;
        bf16x8 af[4][2];                       // A-half frags, reused across nh pair
#pragma unroll
        for (int ph = 0; ph < 4; ++ph) {
            const int mh = ph >> 1, nh = ph & 1;
            if (nh == 0) {                     // A-half mh: 8 x ds_read_b128
#pragma unroll
                for (int m = 0; m < 4; ++m) {
                    int ro = baseA + mh * 4096 + m * 1024;
                    af[m][0] = *(const bf16x8*)&As[ro + swz0];
                    af[m][1] = *(const bf16x8*)&As[ro + swz1];
                }
            }
            bf16x8 bq[2][2];                   // B-half nh: 4 x ds_read_b128
#pragma unroll
            for (int n = 0; n < 2; ++n) {
                int ro = baseB + nh * 2048 + n * 1024;
                bq[n][0] = *(const bf16x8*)&Bs[ro + swz0];
                bq[n][1] = *(const bf16x8*)&Bs[ro + swz1];
            }
            // stage (issue-only; see ledger in header comment)
            if (ph == 0)      { if (t + 1 < NT) STAGE(1, 0, t + 1); }
            else if (ph == 1) { if (t + 1 < NT) STAGE(1, 1, t + 1); }
            else if (ph == 3 && t + 2 < NT) { STAGE(0, 0, t + 2); STAGE(0, 1, t + 2); }

            __builtin_amdgcn_s_barrier();
            __builtin_amdgcn_sched_barrier(0);
            __builtin_amdgcn_s_setprio(1);
#pragma unroll
            for (int m = 0; m < 4; ++m)
#pragma unroll
                for (int n = 0; n < 2; ++n) {
                    f32x4* a = &acc[mh * 4 + m][nh * 2 + n];
                    *a = __builtin_amdgcn_mfma_f32_16x16x32_bf16(af[m][0], bq[n][0], *a, 0, 0, 0);
                    *a = __builtin_amdgcn_mfma_f32_16x16x32_bf16(af[m][1], bq[n][1], *a, 0, 0, 0);
                }
            __builtin_amdgcn_s_setprio(0);
            if (ph == 3) {                     // counted wait, once per K-tile
                if (t + 2 < NT)      asm volatile("s_waitcnt vmcnt(4)" ::: "memory");
                else if (t + 1 < NT) asm volatile("s_waitcnt vmcnt(0)" ::: "memory");
            }
            __builtin_amdgcn_s_barrier();
            __builtin_amdgcn_sched_barrier(0);
        }
    }

    // epilogue: C/D row = 4*quad + reg, col = lane&15
#pragma unroll
    for (int jn = 0; jn < 4; ++jn) {
        size_t col = n0 + wn * 64 + jn * 16 + cL;
        float bb = 0.0f;
        if (EPI == 1) bb = bias[col];
#pragma unroll
        for (int im = 0; im < 8; ++im) {
            size_t r = m0 + wm * 128 + im * 16 + 4 * q;
#pragma unroll
            for (int ii = 0; ii < 4; ++ii) {
                float v = acc[im][jn][ii];
                if (EPI == 0)
                    ((__hip_bfloat16*)Cout)[(r + ii) * N + col] = __float2bfloat16(v * scale);
                else
                    ((float*)Cout)[(r + ii) * N + col] = v + bb;
            }
        }
    }
}

// ---------------------------------------------- flash attention, LDS-staged K/V
// block = 256 threads / 4 waves, 128 S-rows (32/wave) for one (b,h).
// T in 8 chunks of 64: K-chunk [t][d] 8KB + V-chunk [d][t] 8KB staged via
// global_load_lds, 16B units XOR-swizzled by row (2-way-free frag reads).
// No-max softmax (scores ~N(0,0.36)); P via per-wave LDS round-trip.
__global__ __launch_bounds__(256, 4) void attn_kernel(const __hip_bfloat16* __restrict__ Qs,
                                                      const __hip_bfloat16* __restrict__ Kg,
                                                      const __hip_bfloat16* __restrict__ Vt,
                                                      __hip_bfloat16* __restrict__ Oc) {
    __shared__ __bf16 Ks[64 * 64];   // [t=64][d=64], swizzled units
    __shared__ __bf16 Vs[64 * 64];   // [d=64][t=64], swizzled units
    __shared__ __bf16 Ps[4][1024];   // per-wave 2KB: two 16x32 A-frag blocks (mi=0,1)
    int tid = threadIdx.x;
    int w = tid >> 6, lane = tid & 63, q = lane >> 4, cL = lane & 15;
    int bh = blockIdx.y;
    int b = bh >> 4, h = bh & 15, g = h >> 3;
    int s0 = blockIdx.x * 128 + w * 32;

    const __bf16* Qb = (const __bf16*)Qs;
    const __bf16* Kb = (const __bf16*)Kg + (size_t)(b * KVH_ + g) * T_ * HD_;
    const __bf16* Vb = (const __bf16*)Vt + (size_t)(b * KVH_ + g) * HD_ * T_;
    __bf16* pw = &Ps[w][0];

    // staging source offsets (elements), constant over chunks; add t0*64 (K) / t0 (V)
    int ksoff[2], vsoff[2];
#pragma unroll
    for (int it = 0; it < 2; it++) {
        int U = tid + it * 256;                 // dest 16B unit
        int r = U >> 3, us = (U & 7) ^ (r & 7); // row, swizzled source unit
        ksoff[it] = r * HD_ + us * 8;           // K: row=t_loc (64 elem rows)
        vsoff[it] = r * T_  + us * 8;           // V: row=d     (512 elem rows)
    }

    // Q A-fragments: 2 m-frags of 16 rows; k = d (2 halves of 32). Q pre-scaled 1/8.
    bf16x8 aq[2][2];
#pragma unroll
    for (int mi = 0; mi < 2; mi++) {
        size_t base = ((size_t)(b * S_) + s0 + mi * 16 + cL) * DM_ + h * HD_ + 8 * q;
        aq[mi][0] = *(const bf16x8*)(Qb + base);
        aq[mi][1] = *(const bf16x8*)(Qb + base + 32);
    }

    float lpart[2][4] = {};
    f32x4 oacc[2][4] = {};

#pragma unroll 1
    for (int tc = 0; tc < 8; tc++) {          // T-chunk of 64
        int t0 = tc * 64;
#pragma unroll
        for (int it = 0; it < 2; it++) {
            int U = tid + it * 256;
            __builtin_amdgcn_global_load_lds(
                (const GLOBAL_AS void*)(Kb + (size_t)t0 * HD_ + ksoff[it]),
                (LDS_AS void*)(&Ks[U * 8]), 16, 0, 0);
            __builtin_amdgcn_global_load_lds(
                (const GLOBAL_AS void*)(Vb + t0 + vsoff[it]),
                (LDS_AS void*)(&Vs[U * 8]), 16, 0, 0);
        }
        __syncthreads();

        // scores S[32 x 64] = Q * K^T ; K-frag units swizzled: unit u at u^(R&7)
        f32x4 sc[2][4];
#pragma unroll
        for (int nt = 0; nt < 4; nt++) {
            int R = 16 * nt + cL;
            bf16x8 k0 = *(const bf16x8*)&Ks[R * 64 + ((q ^ (R & 7)) * 8)];
            bf16x8 k1 = *(const bf16x8*)&Ks[R * 64 + (((4 + q) ^ (R & 7)) * 8)];
#pragma unroll
            for (int mi = 0; mi < 2; mi++) {
                f32x4 a = {0.f, 0.f, 0.f, 0.f};
                a = __builtin_amdgcn_mfma_f32_16x16x32_bf16(aq[mi][0], k0, a, 0, 0, 0);
                a = __builtin_amdgcn_mfma_f32_16x16x32_bf16(aq[mi][1], k1, a, 0, 0, 0);
                sc[mi][nt] = a;
            }
        }

        // exp (no max-sub), per-lane partial row sums
#pragma unroll
        for (int mi = 0; mi < 2; mi++)
#pragma unroll
            for (int i = 0; i < 4; i++) {
                float ls = 0.f;
#pragma unroll
                for (int nt = 0; nt < 4; nt++) {
                    float e = __expf(sc[mi][nt][i]); sc[mi][nt][i] = e; ls += e;
                }
                lpart[mi][i] += ls;
            }

        // P round-trip + PV per 32-t sub-chunk (same-wave LDS, no barrier)
#pragma unroll
        for (int ksc = 0; ksc < 2; ksc++) {
#pragma unroll
            for (int mi = 0; mi < 2; mi++)
#pragma unroll
                for (int half = 0; half < 2; half++) {
                    int nt = 2 * ksc + half;
                    int tin = half * 16 + cL;
                    int off = mi * 512 + (((tin >> 3) * 16 + 4 * q) * 8) + (tin & 7);
#pragma unroll
                    for (int i = 0; i < 4; i++)
                        pw[off + i * 8] = (__bf16)sc[mi][nt][i];
                }
            bf16x8 pa0 = *(const bf16x8*)&pw[lane * 8];
            bf16x8 pa1 = *(const bf16x8*)&pw[512 + lane * 8];
#pragma unroll
            for (int nd = 0; nd < 4; nd++) {
                int D = 16 * nd + cL;
                bf16x8 bv = *(const bf16x8*)&Vs[D * 64 + (((4 * ksc + q) ^ (D & 7)) * 8)];
                oacc[0][nd] = __builtin_amdgcn_mfma_f32_16x16x32_bf16(pa0, bv, oacc[0][nd], 0, 0, 0);
                oacc[1][nd] = __builtin_amdgcn_mfma_f32_16x16x32_bf16(pa1, bv, oacc[1][nd], 0, 0, 0);
            }
        }
        __syncthreads();   // all waves done with Ks/Vs before restage
    }

    // row-sum reduce across the 16 lanes sharing quad q, then write O
#pragma unroll
    for (int mi = 0; mi < 2; mi++) {
        float rinv[4];
#pragma unroll
        for (int i = 0; i < 4; i++) {
            float l = lpart[mi][i];
            l += __shfl_xor(l, 1); l += __shfl_xor(l, 2);
            l += __shfl_xor(l, 4); l += __shfl_xor(l, 8);
            rinv[i] = 1.0f / l;
        }
#pragma unroll
        for (int nd = 0; nd < 4; nd++)
#pragma unroll
            for (int i = 0; i < 4; i++) {
                float v = oacc[mi][nd][i] * rinv[i];
                size_t s = (size_t)(b * S_) + s0 + mi * 16 + 4 * q + i;
                Oc[s * DM_ + h * HD_ + nd * 16 + cL] = __float2bfloat16(v);
            }
    }
}

// ---------------------------------------------------------------------- launch
extern "C" void kernel_launch(void* const* d_in, const int* in_sizes, int n_in,
                              void* d_out, int out_size, void* d_ws, size_t ws_size,
                              hipStream_t stream) {
    const float* x    = (const float*)d_in[0];
    const float* text = (const float*)d_in[1];
    const float* lnw  = (const float*)d_in[2];
    const float* lnb  = (const float*)d_in[3];
    const float* Wq   = (const float*)d_in[4];
    const float* Wkv  = (const float*)d_in[5];
    const float* Wout = (const float*)d_in[6];
    const float* bout = (const float*)d_in[7];

    char* ws = (char*)d_ws;
    __hip_bfloat16* xbf = (__hip_bfloat16*)(ws);              // 33.5 MB; reused as Oc
    __hip_bfloat16* Qs  = (__hip_bfloat16*)(ws + 33554432);   // 33.5 MB
    __hip_bfloat16* Wqt = (__hip_bfloat16*)(ws + 67108864);   // 2 MB
    __hip_bfloat16* Wot = (__hip_bfloat16*)(ws + 69206016);   // 2 MB
    __hip_bfloat16* Kg  = (__hip_bfloat16*)(ws + 71303168);   // 0.5 MB
    __hip_bfloat16* Vtp = (__hip_bfloat16*)(ws + 71827456);   // 0.5 MB
    // tnb / Wkvt parked inside the Qs region (dead until gemm256<0> writes Qs,
    // which is strictly after kv_gemm completes on this stream)
    __hip_bfloat16* tnb  = (__hip_bfloat16*)(ws + 33554432);             // 3.1 MB
    __hip_bfloat16* Wkvt = (__hip_bfloat16*)(ws + 33554432 + 3145728);   // 0.4 MB

    cast_f32_bf16<<<dim3((B_ * S_ * DM_) / 4 / 256), dim3(256), 0, stream>>>(x, xbf);
    transpose_cast<<<dim3(32, 32), dim3(32, 8), 0, stream>>>(Wq, Wqt, DM_, DM_);
    transpose_cast<<<dim3(32, 32), dim3(32, 8), 0, stream>>>(Wout, Wot, DM_, DM_);
    transpose_cast<<<dim3(8, 24), dim3(32, 8), 0, stream>>>(Wkv, Wkvt, DT_, 2 * KVH_ * HD_);

    // LayerNorm -> tnb bf16 [2048][768]
    ln_norm<<<dim3(B_ * T_ / 8), dim3(256), 0, stream>>>(text, lnw, lnb, tnb);

    // KV projection (MFMA) -> Kg [b,g,t,d], Vt [b,g,d,t]
    kv_gemm<<<dim3(2 * KVH_ * HD_ / 64, B_ * T_ / 64), dim3(256), 0, stream>>>(
        tnb, Wkvt, Kg, Vtp);

    // Q = (x @ Wq) * (1/sqrt(64))  [bf16]  -- grid (1024/256, 16384/256) = 256 blocks
    gemm256<0><<<dim3(DM_ / 256, (B_ * S_) / 256), dim3(512), 0, stream>>>(
        xbf, Wqt, (void*)Qs, nullptr, 0.125f, B_ * S_, DM_, DM_);

    // attention -> Oc (reuses xbf region; x is dead after Q-proj)
    attn_kernel<<<dim3(S_ / 128, B_ * H_), dim3(256), 0, stream>>>(Qs, Kg, Vtp, xbf);

    // out = Oc @ Wout + bout  [f32]
    gemm256<1><<<dim3(DM_ / 256, (B_ * S_) / 256), dim3(512), 0, stream>>>(
        xbf, Wot, d_out, bout, 1.0f, B_ * S_, DM_, DM_);
}

// Round 6
// 300.140 us; speedup vs baseline: 1.2267x; 1.0051x over previous
//
#include <hip/hip_runtime.h>
#include <hip/hip_bf16.h>

// MQA cross-attention, MI355X bf16-MFMA pipeline.
// Round 10: bisection after two race-failures (r8, r9 both combined
// counted-vmcnt raw-barrier dbuf + P-layout changes; both failed non-
// deterministically). This round = the PASSING 301.7µs kernel + ONE delta:
// K/V double-buffer in attn synced by plain __syncthreads() (T3 minimum
// 2-phase: STAGE(buf^1,t+1); compute buf; __syncthreads). No raw barriers,
// no counted vmcnt, no P-path changes. gemm256/kv_gemm/ln_norm/casts
// byte-identical to the passing version.
// B=4 S=4096 T=512 D=1024 Dtext=768 H=16 KVH=2 HD=64 REP=8

#define B_    4
#define S_    4096
#define T_    512
#define DM_   1024
#define DT_   768
#define H_    16
#define KVH_  2
#define HD_   64

#define GLOBAL_AS __attribute__((address_space(1)))
#define LDS_AS    __attribute__((address_space(3)))

typedef __bf16 bf16x8 __attribute__((ext_vector_type(8)));
typedef float  f32x4  __attribute__((ext_vector_type(4)));

// ---------------------------------------------------------------- cast x -> bf16
__global__ __launch_bounds__(256) void cast_f32_bf16(const float* __restrict__ in,
                                                     __hip_bfloat16* __restrict__ out) {
    int i = blockIdx.x * 256 + threadIdx.x;          // one float4 per thread
    float4 v = ((const float4*)in)[i];
    union { ushort4 u; __hip_bfloat16 h[4]; } p;
    p.h[0] = __float2bfloat16(v.x);
    p.h[1] = __float2bfloat16(v.y);
    p.h[2] = __float2bfloat16(v.z);
    p.h[3] = __float2bfloat16(v.w);
    ((ushort4*)out)[i] = p.u;
}

// ---------------------------------------------- transpose+cast W[R][C] -> Wt[C][R] bf16
__global__ __launch_bounds__(256) void transpose_cast(const float* __restrict__ in,
                                                      __hip_bfloat16* __restrict__ out,
                                                      int R, int C) {
    __shared__ float tile[32][33];
    int tx = threadIdx.x, ty = threadIdx.y;           // block (32,8)
    int r0 = blockIdx.y * 32, c0 = blockIdx.x * 32;
#pragma unroll
    for (int k = 0; k < 4; k++)
        tile[ty + 8 * k][tx] = in[(size_t)(r0 + ty + 8 * k) * C + c0 + tx];
    __syncthreads();
#pragma unroll
    for (int k = 0; k < 4; k++)
        out[(size_t)(c0 + ty + 8 * k) * R + r0 + tx] = __float2bfloat16(tile[tx][ty + 8 * k]);
}

// --------------------------------- LayerNorm(text) -> tnb bf16 [B*T][768]
// one row per wave (2 rows sequentially), float4 loads, 64-lane shuffle reduce.
__global__ __launch_bounds__(256) void ln_norm(const float* __restrict__ text,
                                               const float* __restrict__ lnw,
                                               const float* __restrict__ lnb,
                                               __hip_bfloat16* __restrict__ tnb) {
    int tid = threadIdx.x;
    int w = tid >> 6, lane = tid & 63;
    int row0 = blockIdx.x * 8 + w * 2;               // 8 rows/block, 2 rows/wave
#pragma unroll
    for (int rr = 0; rr < 2; ++rr) {
        int row = row0 + rr;
        const float4* src = (const float4*)(text + (size_t)row * DT_);
        float4 v[3];
        float s = 0.f, s2 = 0.f;
#pragma unroll
        for (int j = 0; j < 3; ++j) {
            v[j] = src[lane + 64 * j];
            s  += v[j].x + v[j].y + v[j].z + v[j].w;
            s2 += v[j].x * v[j].x + v[j].y * v[j].y + v[j].z * v[j].z + v[j].w * v[j].w;
        }
#pragma unroll
        for (int ofs = 1; ofs < 64; ofs <<= 1) {
            s  += __shfl_xor(s, ofs);
            s2 += __shfl_xor(s2, ofs);
        }
        float mu  = s * (1.0f / DT_);
        float var = s2 * (1.0f / DT_) - mu * mu;
        float rs  = rsqrtf(var + 1e-5f);
#pragma unroll
        for (int j = 0; j < 3; ++j) {
            float4 wv = ((const float4*)lnw)[lane + 64 * j];
            float4 bv = ((const float4*)lnb)[lane + 64 * j];
            union { ushort4 u; __hip_bfloat16 h[4]; } p;
            p.h[0] = __float2bfloat16((v[j].x - mu) * rs * wv.x + bv.x);
            p.h[1] = __float2bfloat16((v[j].y - mu) * rs * wv.y + bv.y);
            p.h[2] = __float2bfloat16((v[j].z - mu) * rs * wv.z + bv.z);
            p.h[3] = __float2bfloat16((v[j].w - mu) * rs * wv.w + bv.w);
            ((ushort4*)(tnb + (size_t)row * DT_))[lane + 64 * j] = p.u;
        }
    }
}

// ----------------------- KV projection: C[2048,256] = tnb[2048,768] @ Wkvt[256,768]^T
// bf16 MFMA, 64x64 tile, BK=32, double-buffered LDS, XOR-swizzled 16B units
// (128B super-rows: unit U=(row&1)*4+u stored at U^(sr&7); proven 0-conflict).
// Epilogue scatters to K [b,g,t,d] / Vt [b,g,d,t].
__global__ __launch_bounds__(256) void kv_gemm(const __hip_bfloat16* __restrict__ Atn,
                                               const __hip_bfloat16* __restrict__ Wkvt,
                                               __hip_bfloat16* __restrict__ Kg,
                                               __hip_bfloat16* __restrict__ Vt) {
    __shared__ __bf16 As[2][64 * 32];
    __shared__ __bf16 Bs[2][64 * 32];
    const int tid = threadIdx.x;
    const int w = tid >> 6, lane = tid & 63, q = lane >> 4, cL = lane & 15;
    const size_t m0 = (size_t)blockIdx.y * 64, n0 = (size_t)blockIdx.x * 64;
    const int K = DT_;                 // 768
    const int NT = K / 32;             // 24

    // staging map: one 16B unit per thread per matrix (256 units = 64x32 bf16)
    int srcoff, dstoff;
    {
        int id = tid;
        int sr = id >> 3, U = (id & 7) ^ (sr & 7);
        int row = 2 * sr + (U >> 2), ko = (U & 3) * 8;
        srcoff = row * K + ko;
        dstoff = id * 8;
    }
    const __bf16* Ab = (const __bf16*)Atn + m0 * K;
    const __bf16* Bb = (const __bf16*)Wkvt + n0 * K;

    // fragment LDS element offsets
    auto frag_off = [&](int R) {
        return (R >> 1) * 64 + ((((R & 1) * 4 + q) ^ ((R >> 1) & 7)) * 8);
    };
    const int offA = frag_off(w * 16 + cL);
    int offB[4];
#pragma unroll
    for (int nf = 0; nf < 4; ++nf) offB[nf] = frag_off(nf * 16 + cL);

    f32x4 acc[4] = {};

    auto STAGE = [&](int buf, int t) {
        int k0 = t * 32;
        __builtin_amdgcn_global_load_lds((const GLOBAL_AS void*)(Ab + srcoff + k0),
                                         (LDS_AS void*)(&As[buf][dstoff]), 16, 0, 0);
        __builtin_amdgcn_global_load_lds((const GLOBAL_AS void*)(Bb + srcoff + k0),
                                         (LDS_AS void*)(&Bs[buf][dstoff]), 16, 0, 0);
    };

    STAGE(0, 0);
    __syncthreads();                       // drains vmcnt(0) before barrier
    for (int t = 0; t < NT; ++t) {
        int cur = t & 1;
        if (t + 1 < NT) STAGE(cur ^ 1, t + 1);   // issue next tile (other buffer)
        bf16x8 af = *(const bf16x8*)&As[cur][offA];
#pragma unroll
        for (int nf = 0; nf < 4; ++nf) {
            bf16x8 bf = *(const bf16x8*)&Bs[cur][offB[nf]];
            acc[nf] = __builtin_amdgcn_mfma_f32_16x16x32_bf16(af, bf, acc[nf], 0, 0, 0);
        }
        __syncthreads();                   // next-tile loads landed + reads done
    }

    // epilogue: C/D row = 4*quad + reg, col = lane&15 ; scatter to K/Vt layouts
#pragma unroll
    for (int nf = 0; nf < 4; ++nf) {
        int n = (int)n0 + nf * 16 + cL;
        int isV = n >> 7, g = (n >> 6) & 1, d = n & 63;
#pragma unroll
        for (int ii = 0; ii < 4; ++ii) {
            int m = (int)m0 + w * 16 + 4 * q + ii;
            int b = m >> 9, tt = m & 511;
            __hip_bfloat16 hv = __float2bfloat16(acc[nf][ii]);
            if (!isV) Kg[((size_t)(b * KVH_ + g) * T_ + tt) * HD_ + d] = hv;
            else      Vt[((size_t)(b * KVH_ + g) * HD_ + d) * T_ + tt] = hv;
        }
    }
}

// ------------------------------------------- C[M,N] = A[M,K] * Bt[N,K]^T  (bf16 MFMA)
// 256x256 tile, BK=64, 512 threads / 8 waves (2M x 4N), per-wave 128x64 output.
// Static LDS 128KiB: 2 dbuf slots x (A 256x64 + B 256x64) bf16, rows of 8x16B
// units with unit u stored at u^(row&7) (conflict-free ds_read_b128).
// Per K-tile: 4 phases = C-quadrants (mh,nh). Stage ledger (race-free):
//   ph0: B0(t+1), ph1: B1(t+1) -> other slot; ph3: A0,A1(t+2) -> live slot but
//   issued after ph2's end barrier (all A-reads of live slot complete).
//   End-of-tile vmcnt(4) leaves {A0,A1 of t+2} in flight, guarantees t+1 landed.
// EPI 0: bf16 out, *scale.  EPI 1: f32 out, + bias.
template <int EPI>
__global__ __launch_bounds__(512, 2) void gemm256(const __hip_bfloat16* __restrict__ A,
                                                  const __hip_bfloat16* __restrict__ Bt,
                                                  void* __restrict__ Cout,
                                                  const float* __restrict__ bias,
                                                  float scale, int M, int N, int K) {
    __shared__ __bf16 lds[65536];             // 128 KiB static
    const int tid = threadIdx.x;
    const int w = tid >> 6, lane = tid & 63, q = lane >> 4, cL = lane & 15;
    const int wm = w >> 2, wn = w & 3;        // 2 x 4 wave grid
    const size_t m0 = (size_t)blockIdx.y * 256, n0 = (size_t)blockIdx.x * 256;
    const __bf16* Ab = (const __bf16*)A + m0 * K;
    const __bf16* Bb = (const __bf16*)Bt + n0 * K;
    const int NT = K >> 6;                    // K-tiles of 64

    int srcoff[2], dstoff[2];
#pragma unroll
    for (int it = 0; it < 2; ++it) {
        int id = tid + it * 512;
        int r = id >> 3, u = (id & 7) ^ (r & 7);
        srcoff[it] = r * K + u * 8;
        dstoff[it] = id * 8;
    }

    const int swz0 = ((0 + q) ^ (cL & 7)) * 8;   // kk=0 (cols 0..31) unit
    const int swz1 = ((4 + q) ^ (cL & 7)) * 8;   // kk=1 (cols 32..63) unit
    const int baseA = (wm * 128 + cL) * 64;
    const int baseB = (wn * 64 + cL) * 64;

    f32x4 acc[8][4] = {};

    auto STAGE = [&](int isB, int j, int tt) {   // half-tile (A/B, rows j*128..) of K-tile tt
        const __bf16* g = (isB ? Bb : Ab) + (size_t)j * 128 * K + (size_t)tt * 64;
        const int sb = (tt & 1) * 32768 + isB * 16384 + j * 8192;
#pragma unroll
        for (int it = 0; it < 2; ++it)
            __builtin_amdgcn_global_load_lds(
                (const GLOBAL_AS void*)(g + srcoff[it]),
                (LDS_AS void*)(&lds[sb + dstoff[it]]), 16, 0, 0);
    };

    // prologue: tile0 complete + A-halves of tile1 (as-if issued at "t=-1 ph3")
    STAGE(0, 0, 0); STAGE(0, 1, 0); STAGE(1, 0, 0); STAGE(1, 1, 0);
    if (NT > 1) { STAGE(0, 0, 1); STAGE(0, 1, 1); }
    asm volatile("s_waitcnt vmcnt(4)" ::: "memory");   // tile0 landed; A(1) may fly
    __builtin_amdgcn_s_barrier();
    __builtin_amdgcn_sched_barrier(0);

    for (int t = 0; t < NT; ++t) {
        const int sb = (t & 1) * 32768;
        const __bf16* As = lds + sb;
        const __bf16* Bs = lds + sb + 16384;
        bf16x8 af[4][2];                       // A-half frags, reused across nh pair
#pragma unroll
        for (int ph = 0; ph < 4; ++ph) {
            const int mh = ph >> 1, nh = ph & 1;
            if (nh == 0) {                     // A-half mh: 8 x ds_read_b128
#pragma unroll
                for (int m = 0; m < 4; ++m) {
                    int ro = baseA + mh * 4096 + m * 1024;
                    af[m][0] = *(const bf16x8*)&As[ro + swz0];
                    af[m][1] = *(const bf16x8*)&As[ro + swz1];
                }
            }
            bf16x8 bq[2][2];                   // B-half nh: 4 x ds_read_b128
#pragma unroll
            for (int n = 0; n < 2; ++n) {
                int ro = baseB + nh * 2048 + n * 1024;
                bq[n][0] = *(const bf16x8*)&Bs[ro + swz0];
                bq[n][1] = *(const bf16x8*)&Bs[ro + swz1];
            }
            // stage (issue-only; see ledger in header comment)
            if (ph == 0)      { if (t + 1 < NT) STAGE(1, 0, t + 1); }
            else if (ph == 1) { if (t + 1 < NT) STAGE(1, 1, t + 1); }
            else if (ph == 3 && t + 2 < NT) { STAGE(0, 0, t + 2); STAGE(0, 1, t + 2); }

            __builtin_amdgcn_s_barrier();
            __builtin_amdgcn_sched_barrier(0);
            __builtin_amdgcn_s_setprio(1);
#pragma unroll
            for (int m = 0; m < 4; ++m)
#pragma unroll
                for (int n = 0; n < 2; ++n) {
                    f32x4* a = &acc[mh * 4 + m][nh * 2 + n];
                    *a = __builtin_amdgcn_mfma_f32_16x16x32_bf16(af[m][0], bq[n][0], *a, 0, 0, 0);
                    *a = __builtin_amdgcn_mfma_f32_16x16x32_bf16(af[m][1], bq[n][1], *a, 0, 0, 0);
                }
            __builtin_amdgcn_s_setprio(0);
            if (ph == 3) {                     // counted wait, once per K-tile
                if (t + 2 < NT)      asm volatile("s_waitcnt vmcnt(4)" ::: "memory");
                else if (t + 1 < NT) asm volatile("s_waitcnt vmcnt(0)" ::: "memory");
            }
            __builtin_amdgcn_s_barrier();
            __builtin_amdgcn_sched_barrier(0);
        }
    }

    // epilogue: C/D row = 4*quad + reg, col = lane&15
#pragma unroll
    for (int jn = 0; jn < 4; ++jn) {
        size_t col = n0 + wn * 64 + jn * 16 + cL;
        float bb = 0.0f;
        if (EPI == 1) bb = bias[col];
#pragma unroll
        for (int im = 0; im < 8; ++im) {
            size_t r = m0 + wm * 128 + im * 16 + 4 * q;
#pragma unroll
            for (int ii = 0; ii < 4; ++ii) {
                float v = acc[im][jn][ii];
                if (EPI == 0)
                    ((__hip_bfloat16*)Cout)[(r + ii) * N + col] = __float2bfloat16(v * scale);
                else
                    ((float*)Cout)[(r + ii) * N + col] = v + bb;
            }
        }
    }
}

// ---------------------------------------------- flash attention, LDS-staged K/V
// block = 256 threads / 4 waves, 128 S-rows (32/wave) for one (b,h).
// T in 8 chunks of 64. Round-10 delta: K/V double-buffered with plain
// __syncthreads (T3 minimum 2-phase): STAGE(buf^1, tc+1) at top of body,
// compute on buf, ONE __syncthreads at end (drains vmcnt(0): next chunk
// landed; all waves done reading buf before its restage at tc+1).
// QK^T / exp / P round-trip / PV / epilogue identical to the passing version.
__global__ __launch_bounds__(256, 4) void attn_kernel(const __hip_bfloat16* __restrict__ Qs,
                                                      const __hip_bfloat16* __restrict__ Kg,
                                                      const __hip_bfloat16* __restrict__ Vt,
                                                      __hip_bfloat16* __restrict__ Oc) {
    __shared__ __bf16 Ks[2][64 * 64];   // [t=64][d=64], swizzled units, dbuf
    __shared__ __bf16 Vs[2][64 * 64];   // [d=64][t=64], swizzled units, dbuf
    __shared__ __bf16 Ps[4][1024];      // per-wave 2KB: two 16x32 A-frag blocks (mi=0,1)
    int tid = threadIdx.x;
    int w = tid >> 6, lane = tid & 63, q = lane >> 4, cL = lane & 15;
    int bh = blockIdx.y;
    int b = bh >> 4, h = bh & 15, g = h >> 3;
    int s0 = blockIdx.x * 128 + w * 32;

    const __bf16* Qb = (const __bf16*)Qs;
    const __bf16* Kb = (const __bf16*)Kg + (size_t)(b * KVH_ + g) * T_ * HD_;
    const __bf16* Vb = (const __bf16*)Vt + (size_t)(b * KVH_ + g) * HD_ * T_;
    __bf16* pw = &Ps[w][0];

    // staging source offsets (elements), constant over chunks; add t0*64 (K) / t0 (V)
    int ksoff[2], vsoff[2];
#pragma unroll
    for (int it = 0; it < 2; it++) {
        int U = tid + it * 256;                 // dest 16B unit
        int r = U >> 3, us = (U & 7) ^ (r & 7); // row, swizzled source unit
        ksoff[it] = r * HD_ + us * 8;           // K: row=t_loc (64 elem rows)
        vsoff[it] = r * T_  + us * 8;           // V: row=d     (512 elem rows)
    }

    auto STAGE = [&](int bufi, int tc) {
        int t0 = tc * 64;
#pragma unroll
        for (int it = 0; it < 2; it++) {
            int U = tid + it * 256;
            __builtin_amdgcn_global_load_lds(
                (const GLOBAL_AS void*)(Kb + (size_t)t0 * HD_ + ksoff[it]),
                (LDS_AS void*)(&Ks[bufi][U * 8]), 16, 0, 0);
            __builtin_amdgcn_global_load_lds(
                (const GLOBAL_AS void*)(Vb + t0 + vsoff[it]),
                (LDS_AS void*)(&Vs[bufi][U * 8]), 16, 0, 0);
        }
    };

    // Q A-fragments: 2 m-frags of 16 rows; k = d (2 halves of 32). Q pre-scaled 1/8.
    bf16x8 aq[2][2];
#pragma unroll
    for (int mi = 0; mi < 2; mi++) {
        size_t base = ((size_t)(b * S_) + s0 + mi * 16 + cL) * DM_ + h * HD_ + 8 * q;
        aq[mi][0] = *(const bf16x8*)(Qb + base);
        aq[mi][1] = *(const bf16x8*)(Qb + base + 32);
    }

    float lpart[2][4] = {};
    f32x4 oacc[2][4] = {};

    STAGE(0, 0);
    __syncthreads();                           // chunk 0 landed (all waves)
#pragma unroll 1
    for (int tc = 0; tc < 8; tc++) {          // T-chunk of 64
        int bufi = tc & 1;
        if (tc + 1 < 8) STAGE(bufi ^ 1, tc + 1);   // issue next chunk (other buffer)

        // scores S[32 x 64] = Q * K^T ; K-frag units swizzled: unit u at u^(R&7)
        f32x4 sc[2][4];
#pragma unroll
        for (int nt = 0; nt < 4; nt++) {
            int R = 16 * nt + cL;
            bf16x8 k0 = *(const bf16x8*)&Ks[bufi][R * 64 + ((q ^ (R & 7)) * 8)];
            bf16x8 k1 = *(const bf16x8*)&Ks[bufi][R * 64 + (((4 + q) ^ (R & 7)) * 8)];
#pragma unroll
            for (int mi = 0; mi < 2; mi++) {
                f32x4 a = {0.f, 0.f, 0.f, 0.f};
                a = __builtin_amdgcn_mfma_f32_16x16x32_bf16(aq[mi][0], k0, a, 0, 0, 0);
                a = __builtin_amdgcn_mfma_f32_16x16x32_bf16(aq[mi][1], k1, a, 0, 0, 0);
                sc[mi][nt] = a;
            }
        }

        // exp (no max-sub), per-lane partial row sums
#pragma unroll
        for (int mi = 0; mi < 2; mi++)
#pragma unroll
            for (int i = 0; i < 4; i++) {
                float ls = 0.f;
#pragma unroll
                for (int nt = 0; nt < 4; nt++) {
                    float e = __expf(sc[mi][nt][i]); sc[mi][nt][i] = e; ls += e;
                }
                lpart[mi][i] += ls;
            }

        // P round-trip + PV per 32-t sub-chunk (same-wave LDS, no barrier)
#pragma unroll
        for (int ksc = 0; ksc < 2; ksc++) {
#pragma unroll
            for (int mi = 0; mi < 2; mi++)
#pragma unroll
                for (int half = 0; half < 2; half++) {
                    int nt = 2 * ksc + half;
                    int tin = half * 16 + cL;
                    int off = mi * 512 + (((tin >> 3) * 16 + 4 * q) * 8) + (tin & 7);
#pragma unroll
                    for (int i = 0; i < 4; i++)
                        pw[off + i * 8] = (__bf16)sc[mi][nt][i];
                }
            bf16x8 pa0 = *(const bf16x8*)&pw[lane * 8];
            bf16x8 pa1 = *(const bf16x8*)&pw[512 + lane * 8];
#pragma unroll
            for (int nd = 0; nd < 4; nd++) {
                int D = 16 * nd + cL;
                bf16x8 bv = *(const bf16x8*)&Vs[bufi][D * 64 + (((4 * ksc + q) ^ (D & 7)) * 8)];
                oacc[0][nd] = __builtin_amdgcn_mfma_f32_16x16x32_bf16(pa0, bv, oacc[0][nd], 0, 0, 0);
                oacc[1][nd] = __builtin_amdgcn_mfma_f32_16x16x32_bf16(pa1, bv, oacc[1][nd], 0, 0, 0);
            }
        }
        __syncthreads();   // next chunk landed (vmcnt0) + all waves done with buf
    }

    // row-sum reduce across the 16 lanes sharing quad q, then write O
#pragma unroll
    for (int mi = 0; mi < 2; mi++) {
        float rinv[4];
#pragma unroll
        for (int i = 0; i < 4; i++) {
            float l = lpart[mi][i];
            l += __shfl_xor(l, 1); l += __shfl_xor(l, 2);
            l += __shfl_xor(l, 4); l += __shfl_xor(l, 8);
            rinv[i] = 1.0f / l;
        }
#pragma unroll
        for (int nd = 0; nd < 4; nd++)
#pragma unroll
            for (int i = 0; i < 4; i++) {
                float v = oacc[mi][nd][i] * rinv[i];
                size_t s = (size_t)(b * S_) + s0 + mi * 16 + 4 * q + i;
                Oc[s * DM_ + h * HD_ + nd * 16 + cL] = __float2bfloat16(v);
            }
    }
}

// ---------------------------------------------------------------------- launch
extern "C" void kernel_launch(void* const* d_in, const int* in_sizes, int n_in,
                              void* d_out, int out_size, void* d_ws, size_t ws_size,
                              hipStream_t stream) {
    const float* x    = (const float*)d_in[0];
    const float* text = (const float*)d_in[1];
    const float* lnw  = (const float*)d_in[2];
    const float* lnb  = (const float*)d_in[3];
    const float* Wq   = (const float*)d_in[4];
    const float* Wkv  = (const float*)d_in[5];
    const float* Wout = (const float*)d_in[6];
    const float* bout = (const float*)d_in[7];

    char* ws = (char*)d_ws;
    __hip_bfloat16* xbf = (__hip_bfloat16*)(ws);              // 33.5 MB; reused as Oc
    __hip_bfloat16* Qs  = (__hip_bfloat16*)(ws + 33554432);   // 33.5 MB
    __hip_bfloat16* Wqt = (__hip_bfloat16*)(ws + 67108864);   // 2 MB
    __hip_bfloat16* Wot = (__hip_bfloat16*)(ws + 69206016);   // 2 MB
    __hip_bfloat16* Kg  = (__hip_bfloat16*)(ws + 71303168);   // 0.5 MB
    __hip_bfloat16* Vtp = (__hip_bfloat16*)(ws + 71827456);   // 0.5 MB
    // tnb / Wkvt parked inside the Qs region (dead until gemm256<0> writes Qs,
    // which is strictly after kv_gemm completes on this stream)
    __hip_bfloat16* tnb  = (__hip_bfloat16*)(ws + 33554432);             // 3.1 MB
    __hip_bfloat16* Wkvt = (__hip_bfloat16*)(ws + 33554432 + 3145728);   // 0.4 MB

    cast_f32_bf16<<<dim3((B_ * S_ * DM_) / 4 / 256), dim3(256), 0, stream>>>(x, xbf);
    transpose_cast<<<dim3(32, 32), dim3(32, 8), 0, stream>>>(Wq, Wqt, DM_, DM_);
    transpose_cast<<<dim3(32, 32), dim3(32, 8), 0, stream>>>(Wout, Wot, DM_, DM_);
    transpose_cast<<<dim3(8, 24), dim3(32, 8), 0, stream>>>(Wkv, Wkvt, DT_, 2 * KVH_ * HD_);

    // LayerNorm -> tnb bf16 [2048][768]
    ln_norm<<<dim3(B_ * T_ / 8), dim3(256), 0, stream>>>(text, lnw, lnb, tnb);

    // KV projection (MFMA) -> Kg [b,g,t,d], Vt [b,g,d,t]
    kv_gemm<<<dim3(2 * KVH_ * HD_ / 64, B_ * T_ / 64), dim3(256), 0, stream>>>(
        tnb, Wkvt, Kg, Vtp);

    // Q = (x @ Wq) * (1/sqrt(64))  [bf16]  -- grid (1024/256, 16384/256) = 256 blocks
    gemm256<0><<<dim3(DM_ / 256, (B_ * S_) / 256), dim3(512), 0, stream>>>(
        xbf, Wqt, (void*)Qs, nullptr, 0.125f, B_ * S_, DM_, DM_);

    // attention -> Oc (reuses xbf region; x is dead after Q-proj)
    attn_kernel<<<dim3(S_ / 128, B_ * H_), dim3(256), 0, stream>>>(Qs, Kg, Vtp, xbf);

    // out = Oc @ Wout + bout  [f32]
    gemm256<1><<<dim3(DM_ / 256, (B_ * S_) / 256), dim3(512), 0, stream>>>(
        xbf, Wot, d_out, bout, 1.0f, B_ * S_, DM_, DM_);
}